// Round 1
// baseline (398.775 us; speedup 1.0000x reference)
//
#include <hip/hip_runtime.h>

#define N_NODES 16384
#define N_EDGES 524288

typedef _Float16 half8 __attribute__((ext_vector_type(8)));
typedef float floatx16 __attribute__((ext_vector_type(16)));

// ---------------- CSR build ----------------

__global__ __launch_bounds__(256) void hist_kernel(const int* __restrict__ dst,
                                                   int* __restrict__ deg) {
  int e = blockIdx.x * 256 + threadIdx.x;
  atomicAdd(&deg[dst[e]], 1);
}

__global__ __launch_bounds__(1024) void scan_kernel(const int* __restrict__ deg,
                                                    int* __restrict__ row_ptr,
                                                    int* __restrict__ cursor,
                                                    float* __restrict__ deg_inv) {
  __shared__ int part[1024];
  int t = threadIdx.x;
  int base = t * 16;
  int loc[16];
  int s = 0;
#pragma unroll
  for (int i = 0; i < 16; ++i) { loc[i] = deg[base + i]; s += loc[i]; }
  part[t] = s;
  __syncthreads();
  for (int off = 1; off < 1024; off <<= 1) {
    int v = (t >= off) ? part[t - off] : 0;
    __syncthreads();
    part[t] += v;
    __syncthreads();
  }
  int run = (t == 0) ? 0 : part[t - 1];
#pragma unroll
  for (int i = 0; i < 16; ++i) {
    row_ptr[base + i] = run;
    cursor[base + i] = run;
    int d = loc[i];
    deg_inv[base + i] = 1.0f / (float)(d > 0 ? d : 1);
    run += d;
  }
  if (t == 1023) row_ptr[N_NODES] = run;
}

__global__ __launch_bounds__(256) void scatter_kernel(const int* __restrict__ src,
                                                      const int* __restrict__ dst,
                                                      int* __restrict__ cursor,
                                                      int* __restrict__ col_idx) {
  int e = blockIdx.x * 256 + threadIdx.x;
  int d = dst[e];
  int pos = atomicAdd(&cursor[d], 1);
  col_idx[pos] = src[e];
}

// ---------------- mean aggregation: one wave per node, lane owns 2 feats (float2) ----------------

__global__ __launch_bounds__(256) void aggregate_kernel(const float* __restrict__ feat,
                                                        const int* __restrict__ row_ptr,
                                                        const int* __restrict__ col_idx,
                                                        const float* __restrict__ deg_inv,
                                                        float* __restrict__ out) {
  int node = blockIdx.x * 4 + (threadIdx.x >> 6);
  int lane = threadIdx.x & 63;
  int beg = row_ptr[node], end = row_ptr[node + 1];
  float ax = 0.f, ay = 0.f;
  int e = beg;
  for (; e + 2 <= end; e += 2) {
    int s0 = col_idx[e];
    int s1 = col_idx[e + 1];
    float2 v0 = *(const float2*)&feat[(size_t)s0 * 128 + lane * 2];
    float2 v1 = *(const float2*)&feat[(size_t)s1 * 128 + lane * 2];
    ax += v0.x; ay += v0.y;
    ax += v1.x; ay += v1.y;
  }
  if (e < end) {
    int s0 = col_idx[e];
    float2 v0 = *(const float2*)&feat[(size_t)s0 * 128 + lane * 2];
    ax += v0.x; ay += v0.y;
  }
  float inv = deg_inv[node];
  float2 r;
  r.x = ax * inv;
  r.y = ay * inv;
  *(float2*)&out[(size_t)node * 128 + lane * 2] = r;
}

// ---------------- fused SAGE layer: out = aggr@Wl + self@Wr + b (f32 FMA) ----------------

template <int OUTC, int ROWS>
__global__ __launch_bounds__(256) void sage_gemm_kernel(const float* __restrict__ aggr,
                                                        const float* __restrict__ self,
                                                        const float* __restrict__ Wl,
                                                        const float* __restrict__ Wr,
                                                        const float* __restrict__ bias,
                                                        float* __restrict__ out) {
  constexpr int CG = OUTC / 4;   // column groups of 4
  constexpr int RG = 256 / CG;   // row groups
  constexpr int RPT = ROWS / RG; // rows per thread
  __shared__ float l1[ROWS][129];  // +1 pad: avoid row-stride bank conflicts
  __shared__ float l2[ROWS][129];
  int t = threadIdx.x;
  size_t row0 = (size_t)blockIdx.x * ROWS;
  for (int i = t; i < ROWS * 128; i += 256) {
    int r = i >> 7, c = i & 127;
    l1[r][c] = aggr[(row0 + r) * 128 + c];
    l2[r][c] = self[(row0 + r) * 128 + c];
  }
  __syncthreads();
  int c0 = (t % CG) * 4;
  int r0 = (t / CG) * RPT;
  float acc[RPT][4] = {};
#pragma unroll 4
  for (int k = 0; k < 128; ++k) {
    float4 wl = *(const float4*)&Wl[k * OUTC + c0];
    float4 wr = *(const float4*)&Wr[k * OUTC + c0];
#pragma unroll
    for (int r = 0; r < RPT; ++r) {
      float a = l1[r0 + r][k];
      float b = l2[r0 + r][k];
      acc[r][0] += a * wl.x + b * wr.x;
      acc[r][1] += a * wl.y + b * wr.y;
      acc[r][2] += a * wl.z + b * wr.z;
      acc[r][3] += a * wl.w + b * wr.w;
    }
  }
  float4 bv = *(const float4*)&bias[c0];
#pragma unroll
  for (int r = 0; r < RPT; ++r) {
    float4 o;
    o.x = acc[r][0] + bv.x;
    o.y = acc[r][1] + bv.y;
    o.z = acc[r][2] + bv.z;
    o.w = acc[r][3] + bv.w;
    *(float4*)&out[(row0 + r0 + r) * OUTC + c0] = o;
  }
}

// ---------------- row L2-normalize; emit f32 z and f16 copy for MFMA ----------------

__global__ __launch_bounds__(256) void normalize_kernel(const float* __restrict__ h2,
                                                        float* __restrict__ z,
                                                        _Float16* __restrict__ zh) {
  int node = blockIdx.x * 4 + (threadIdx.x >> 6);
  int lane = threadIdx.x & 63;
  float v = h2[(size_t)node * 64 + lane];
  float ss = v * v;
#pragma unroll
  for (int off = 32; off > 0; off >>= 1) ss += __shfl_xor(ss, off);
  float inv = 1.0f / fmaxf(sqrtf(ss), 1e-12f);
  float zv = v * inv;
  z[(size_t)node * 64 + lane] = zv;
  zh[(size_t)node * 64 + lane] = (_Float16)zv;
}

// ---------------- x_ = elu(z @ W_lin + b_lin) ----------------

__global__ __launch_bounds__(256) void lin_elu_kernel(const float* __restrict__ z,
                                                      const float* __restrict__ W,
                                                      const float* __restrict__ bias,
                                                      float* __restrict__ out) {
  __shared__ float lz[32][65];
  int t = threadIdx.x;
  size_t row0 = (size_t)blockIdx.x * 32;
  for (int i = t; i < 32 * 64; i += 256) {
    int r = i >> 6, c = i & 63;
    lz[r][c] = z[(row0 + r) * 64 + c];
  }
  __syncthreads();
  int c0 = (t & 31) * 4;
  int r0 = (t >> 5) * 4;
  float acc[4][4] = {};
#pragma unroll 4
  for (int k = 0; k < 64; ++k) {
    float4 w = *(const float4*)&W[k * 128 + c0];
#pragma unroll
    for (int r = 0; r < 4; ++r) {
      float a = lz[r0 + r][k];
      acc[r][0] += a * w.x;
      acc[r][1] += a * w.y;
      acc[r][2] += a * w.z;
      acc[r][3] += a * w.w;
    }
  }
  float4 bv = *(const float4*)&bias[c0];
#pragma unroll
  for (int r = 0; r < 4; ++r) {
    float v0 = acc[r][0] + bv.x;
    float v1 = acc[r][1] + bv.y;
    float v2 = acc[r][2] + bv.z;
    float v3 = acc[r][3] + bv.w;
    float4 o;
    o.x = v0 > 0.f ? v0 : expm1f(v0);
    o.y = v1 > 0.f ? v1 : expm1f(v1);
    o.z = v2 > 0.f ? v2 : expm1f(v2);
    o.w = v3 > 0.f ? v3 : expm1f(v3);
    *(float4*)&out[(row0 + r0 + r) * 128 + c0] = o;
  }
}

// ---------------- A_pred = sigmoid(z z^T), f16 MFMA 32x32x16, store-bound ----------------
// Block = 4 waves (2x2), each wave computes a 64x64 region as 2x2 MFMA tiles.
// A-frag: lane holds z[rbase + rt*32 + (l&31)][kc*16 + (l>>5)*8 + j]  (8 contiguous f16)
// B-frag: same pattern with the column tile (B = z^T, so B-cols are z rows).
// C/D: col = lane&31, row = (reg&3) + 8*(reg>>2) + 4*(lane>>5).
// z z^T is symmetric -> any residual transpose in layout is a no-op.

__global__ __launch_bounds__(256) void apred_kernel(const _Float16* __restrict__ zh,
                                                    float* __restrict__ out) {
  int t = threadIdx.x;
  int lane = t & 63;
  int w = t >> 6;
  int wr = w >> 1, wc = w & 1;
  int lmod = lane & 31, lhalf = lane >> 5;
  int rbase = blockIdx.y * 128 + wr * 64;
  int cbase = blockIdx.x * 128 + wc * 64;

  half8 af[2][4], bf[2][4];
#pragma unroll
  for (int rt = 0; rt < 2; ++rt) {
#pragma unroll
    for (int kc = 0; kc < 4; ++kc) {
      af[rt][kc] = *(const half8*)&zh[(size_t)(rbase + rt * 32 + lmod) * 64 + kc * 16 + lhalf * 8];
      bf[rt][kc] = *(const half8*)&zh[(size_t)(cbase + rt * 32 + lmod) * 64 + kc * 16 + lhalf * 8];
    }
  }

  floatx16 acc[2][2] = {};
#pragma unroll
  for (int rt = 0; rt < 2; ++rt)
#pragma unroll
    for (int ct = 0; ct < 2; ++ct)
#pragma unroll
      for (int kc = 0; kc < 4; ++kc)
        acc[rt][ct] = __builtin_amdgcn_mfma_f32_32x32x16_f16(af[rt][kc], bf[ct][kc], acc[rt][ct], 0, 0, 0);

#pragma unroll
  for (int rt = 0; rt < 2; ++rt) {
#pragma unroll
    for (int ct = 0; ct < 2; ++ct) {
#pragma unroll
      for (int reg = 0; reg < 16; ++reg) {
        int r = (reg & 3) + 8 * (reg >> 2) + 4 * lhalf;
        float v = acc[rt][ct][reg];
        float sg = __builtin_amdgcn_rcpf(1.0f + __expf(-v));
        size_t addr = (size_t)(rbase + rt * 32 + r) * N_NODES + (cbase + ct * 32 + lmod);
        __builtin_nontemporal_store(sg, &out[addr]);
      }
    }
  }
}

// ---------------- launch ----------------

extern "C" void kernel_launch(void* const* d_in, const int* in_sizes, int n_in,
                              void* d_out, int out_size, void* d_ws, size_t ws_size,
                              hipStream_t stream) {
  const float* x = (const float*)d_in[0];
  const float* W_l1 = (const float*)d_in[1];
  const float* W_r1 = (const float*)d_in[2];
  const float* b1 = (const float*)d_in[3];
  const float* W_l2 = (const float*)d_in[4];
  const float* W_r2 = (const float*)d_in[5];
  const float* b2 = (const float*)d_in[6];
  const float* W_lin = (const float*)d_in[7];
  const float* b_lin = (const float*)d_in[8];
  const int* edge = (const int*)d_in[9];  // [2][E] int32
  const int* esrc = edge;
  const int* edst = edge + N_EDGES;

  // workspace layout (~24.3 MB)
  int* deg = (int*)d_ws;                               // 16384
  int* row_ptr = deg + 16384;                          // 16385 (+pad)
  int* cursor = row_ptr + 16448;                       // 16384
  float* deg_inv = (float*)(cursor + 16384);           // 16384
  int* col_idx = (int*)(deg_inv + 16384);              // E
  float* agg = (float*)(col_idx + N_EDGES);            // N*128
  float* h = agg + (size_t)N_NODES * 128;              // N*128
  float* h2 = h + (size_t)N_NODES * 128;               // N*64
  _Float16* zh = (_Float16*)(h2 + (size_t)N_NODES * 64);  // N*64 f16

  // output layout: [A_pred (N*N)] [z (N*64)] [x_ (N*128)]
  float* A = (float*)d_out;
  float* z = A + (size_t)N_NODES * N_NODES;
  float* xo = z + (size_t)N_NODES * 64;

  hipMemsetAsync(deg, 0, N_NODES * sizeof(int), stream);
  hist_kernel<<<N_EDGES / 256, 256, 0, stream>>>(edst, deg);
  scan_kernel<<<1, 1024, 0, stream>>>(deg, row_ptr, cursor, deg_inv);
  scatter_kernel<<<N_EDGES / 256, 256, 0, stream>>>(esrc, edst, cursor, col_idx);

  aggregate_kernel<<<N_NODES / 4, 256, 0, stream>>>(x, row_ptr, col_idx, deg_inv, agg);
  sage_gemm_kernel<128, 32><<<N_NODES / 32, 256, 0, stream>>>(agg, x, W_l1, W_r1, b1, h);
  aggregate_kernel<<<N_NODES / 4, 256, 0, stream>>>(h, row_ptr, col_idx, deg_inv, agg);
  sage_gemm_kernel<64, 32><<<N_NODES / 32, 256, 0, stream>>>(agg, h, W_l2, W_r2, b2, h2);
  normalize_kernel<<<N_NODES / 4, 256, 0, stream>>>(h2, z, zh);
  lin_elu_kernel<<<N_NODES / 32, 256, 0, stream>>>(z, W_lin, b_lin, xo);

  dim3 grid(N_NODES / 128, N_NODES / 128);
  apred_kernel<<<grid, 256, 0, stream>>>(zh, A);
}

// Round 3
// 352.027 us; speedup vs baseline: 1.1328x; 1.1328x over previous
//
#include <hip/hip_runtime.h>

#define N_NODES 16384
#define N_EDGES 524288

typedef _Float16 half8 __attribute__((ext_vector_type(8)));
typedef float floatx16 __attribute__((ext_vector_type(16)));
typedef float floatx4 __attribute__((ext_vector_type(4)));

// ---------------- CSR build ----------------

__global__ __launch_bounds__(256) void hist_kernel(const int* __restrict__ dst,
                                                   int* __restrict__ deg) {
  int e = blockIdx.x * 256 + threadIdx.x;
  atomicAdd(&deg[dst[e]], 1);
}

__global__ __launch_bounds__(1024) void scan_kernel(const int* __restrict__ deg,
                                                    int* __restrict__ row_ptr,
                                                    int* __restrict__ cursor,
                                                    float* __restrict__ deg_inv) {
  __shared__ int part[1024];
  int t = threadIdx.x;
  int base = t * 16;
  int loc[16];
  int s = 0;
#pragma unroll
  for (int i = 0; i < 16; ++i) { loc[i] = deg[base + i]; s += loc[i]; }
  part[t] = s;
  __syncthreads();
  for (int off = 1; off < 1024; off <<= 1) {
    int v = (t >= off) ? part[t - off] : 0;
    __syncthreads();
    part[t] += v;
    __syncthreads();
  }
  int run = (t == 0) ? 0 : part[t - 1];
#pragma unroll
  for (int i = 0; i < 16; ++i) {
    row_ptr[base + i] = run;
    cursor[base + i] = run;
    int d = loc[i];
    deg_inv[base + i] = 1.0f / (float)(d > 0 ? d : 1);
    run += d;
  }
  if (t == 1023) row_ptr[N_NODES] = run;
}

__global__ __launch_bounds__(256) void scatter_kernel(const int* __restrict__ src,
                                                      const int* __restrict__ dst,
                                                      int* __restrict__ cursor,
                                                      int* __restrict__ col_idx) {
  int e = blockIdx.x * 256 + threadIdx.x;
  int d = dst[e];
  int pos = atomicAdd(&cursor[d], 1);
  col_idx[pos] = src[e];
}

// ---------------- mean aggregation v2: wave/node, shfl-broadcast indices ----------------

__global__ __launch_bounds__(512) void aggregate_kernel(const float* __restrict__ feat,
                                                        const int* __restrict__ row_ptr,
                                                        const int* __restrict__ col_idx,
                                                        const float* __restrict__ deg_inv,
                                                        float* __restrict__ out) {
  int node = blockIdx.x * 8 + (threadIdx.x >> 6);
  int lane = threadIdx.x & 63;
  int beg = row_ptr[node], end = row_ptr[node + 1];
  float ax = 0.f, ay = 0.f;
  for (int base = beg; base < end; base += 64) {
    int rem = end - base;
    int cnt = rem < 64 ? rem : 64;
    int idx = (lane < cnt) ? col_idx[base + lane] : 0;
    int j = 0;
    for (; j + 4 <= cnt; j += 4) {
      int s0 = __shfl(idx, j);
      int s1 = __shfl(idx, j + 1);
      int s2 = __shfl(idx, j + 2);
      int s3 = __shfl(idx, j + 3);
      float2 v0 = *(const float2*)&feat[(size_t)s0 * 128 + lane * 2];
      float2 v1 = *(const float2*)&feat[(size_t)s1 * 128 + lane * 2];
      float2 v2 = *(const float2*)&feat[(size_t)s2 * 128 + lane * 2];
      float2 v3 = *(const float2*)&feat[(size_t)s3 * 128 + lane * 2];
      ax += v0.x + v1.x + v2.x + v3.x;
      ay += v0.y + v1.y + v2.y + v3.y;
    }
    for (; j < cnt; ++j) {
      int s0 = __shfl(idx, j);
      float2 v0 = *(const float2*)&feat[(size_t)s0 * 128 + lane * 2];
      ax += v0.x;
      ay += v0.y;
    }
  }
  float inv = deg_inv[node];
  float2 r;
  r.x = ax * inv;
  r.y = ay * inv;
  *(float2*)&out[(size_t)node * 128 + lane * 2] = r;
}

// ---------------- fused SAGE layer: out = aggr@Wl + self@Wr + b (f32 FMA) ----------------

template <int OUTC, int ROWS>
__global__ __launch_bounds__(256) void sage_gemm_kernel(const float* __restrict__ aggr,
                                                        const float* __restrict__ self,
                                                        const float* __restrict__ Wl,
                                                        const float* __restrict__ Wr,
                                                        const float* __restrict__ bias,
                                                        float* __restrict__ out) {
  constexpr int CG = OUTC / 4;
  constexpr int RG = 256 / CG;
  constexpr int RPT = ROWS / RG;
  __shared__ float l1[ROWS][129];
  __shared__ float l2[ROWS][129];
  int t = threadIdx.x;
  size_t row0 = (size_t)blockIdx.x * ROWS;
  for (int i = t; i < ROWS * 128; i += 256) {
    int r = i >> 7, c = i & 127;
    l1[r][c] = aggr[(row0 + r) * 128 + c];
    l2[r][c] = self[(row0 + r) * 128 + c];
  }
  __syncthreads();
  int c0 = (t % CG) * 4;
  int r0 = (t / CG) * RPT;
  float acc[RPT][4] = {};
#pragma unroll 4
  for (int k = 0; k < 128; ++k) {
    float4 wl = *(const float4*)&Wl[k * OUTC + c0];
    float4 wr = *(const float4*)&Wr[k * OUTC + c0];
#pragma unroll
    for (int r = 0; r < RPT; ++r) {
      float a = l1[r0 + r][k];
      float b = l2[r0 + r][k];
      acc[r][0] += a * wl.x + b * wr.x;
      acc[r][1] += a * wl.y + b * wr.y;
      acc[r][2] += a * wl.z + b * wr.z;
      acc[r][3] += a * wl.w + b * wr.w;
    }
  }
  float4 bv = *(const float4*)&bias[c0];
#pragma unroll
  for (int r = 0; r < RPT; ++r) {
    float4 o;
    o.x = acc[r][0] + bv.x;
    o.y = acc[r][1] + bv.y;
    o.z = acc[r][2] + bv.z;
    o.w = acc[r][3] + bv.w;
    *(float4*)&out[(row0 + r0 + r) * OUTC + c0] = o;
  }
}

// ---------------- row L2-normalize; emit f32 z and f16 copy for MFMA ----------------

__global__ __launch_bounds__(256) void normalize_kernel(const float* __restrict__ h2,
                                                        float* __restrict__ z,
                                                        _Float16* __restrict__ zh) {
  int node = blockIdx.x * 4 + (threadIdx.x >> 6);
  int lane = threadIdx.x & 63;
  float v = h2[(size_t)node * 64 + lane];
  float ss = v * v;
#pragma unroll
  for (int off = 32; off > 0; off >>= 1) ss += __shfl_xor(ss, off);
  float inv = 1.0f / fmaxf(sqrtf(ss), 1e-12f);
  float zv = v * inv;
  z[(size_t)node * 64 + lane] = zv;
  zh[(size_t)node * 64 + lane] = (_Float16)zv;
}

// ---------------- x_ = elu(z @ W_lin + b_lin) ----------------

__global__ __launch_bounds__(256) void lin_elu_kernel(const float* __restrict__ z,
                                                      const float* __restrict__ W,
                                                      const float* __restrict__ bias,
                                                      float* __restrict__ out) {
  __shared__ float lz[32][65];
  int t = threadIdx.x;
  size_t row0 = (size_t)blockIdx.x * 32;
  for (int i = t; i < 32 * 64; i += 256) {
    int r = i >> 6, c = i & 63;
    lz[r][c] = z[(row0 + r) * 64 + c];
  }
  __syncthreads();
  int c0 = (t & 31) * 4;
  int r0 = (t >> 5) * 4;
  float acc[4][4] = {};
#pragma unroll 4
  for (int k = 0; k < 64; ++k) {
    float4 w = *(const float4*)&W[k * 128 + c0];
#pragma unroll
    for (int r = 0; r < 4; ++r) {
      float a = lz[r0 + r][k];
      acc[r][0] += a * w.x;
      acc[r][1] += a * w.y;
      acc[r][2] += a * w.z;
      acc[r][3] += a * w.w;
    }
  }
  float4 bv = *(const float4*)&bias[c0];
#pragma unroll
  for (int r = 0; r < 4; ++r) {
    float v0 = acc[r][0] + bv.x;
    float v1 = acc[r][1] + bv.y;
    float v2 = acc[r][2] + bv.z;
    float v3 = acc[r][3] + bv.w;
    float4 o;
    o.x = v0 > 0.f ? v0 : expm1f(v0);
    o.y = v1 > 0.f ? v1 : expm1f(v1);
    o.z = v2 > 0.f ? v2 : expm1f(v2);
    o.w = v3 > 0.f ? v3 : expm1f(v3);
    *(float4*)&out[(row0 + r0 + r) * 128 + c0] = o;
  }
}

// ---------------- A_pred = sigmoid(z z^T), f16 MFMA, LDS-staged coalesced stores ----------
// Block: 128 rows x 256 cols, 512 threads = 8 waves (2 row x 4 col), each wave
// a 64x64 region as 2x2 MFMA 32x32x16 tiles. Epilogue: 4 bands of 32 rows
// staged via 32 KB LDS; stores are 64-lane float4 = 1 KB contiguous
// nontemporal wave stores (native vector type for the builtin).

__global__ __launch_bounds__(512, 4) void apred_kernel(const _Float16* __restrict__ zh,
                                                       float* __restrict__ out) {
  __shared__ float lds[32][256];
  int t = threadIdx.x;
  int lane = t & 63;
  int w = t >> 6;
  int wr = w >> 2, wc = w & 3;
  int lmod = lane & 31, lhalf = lane >> 5;
  int rbase = blockIdx.y * 128;
  int cbase = blockIdx.x * 256;
  int rw = rbase + wr * 64;
  int cw = cbase + wc * 64;

  floatx16 acc[2][2] = {};
#pragma unroll
  for (int kc = 0; kc < 4; ++kc) {
    int ko = kc * 16 + lhalf * 8;
    half8 a0 = *(const half8*)&zh[(size_t)(rw + lmod) * 64 + ko];
    half8 a1 = *(const half8*)&zh[(size_t)(rw + 32 + lmod) * 64 + ko];
    half8 b0 = *(const half8*)&zh[(size_t)(cw + lmod) * 64 + ko];
    half8 b1 = *(const half8*)&zh[(size_t)(cw + 32 + lmod) * 64 + ko];
    acc[0][0] = __builtin_amdgcn_mfma_f32_32x32x16_f16(a0, b0, acc[0][0], 0, 0, 0);
    acc[0][1] = __builtin_amdgcn_mfma_f32_32x32x16_f16(a0, b1, acc[0][1], 0, 0, 0);
    acc[1][0] = __builtin_amdgcn_mfma_f32_32x32x16_f16(a1, b0, acc[1][0], 0, 0, 0);
    acc[1][1] = __builtin_amdgcn_mfma_f32_32x32x16_f16(a1, b1, acc[1][1], 0, 0, 0);
  }

  // 4 bands of 32 rows; band b owned by waves with wr == b>>1, using acc[b&1][*]
#pragma unroll
  for (int b = 0; b < 4; ++b) {
    if (wr == (b >> 1)) {
#pragma unroll
      for (int ct = 0; ct < 2; ++ct) {
#pragma unroll
        for (int reg = 0; reg < 16; ++reg) {
          int r = (reg & 3) + 8 * (reg >> 2) + 4 * lhalf;
          lds[r][wc * 64 + ct * 32 + lmod] = acc[b & 1][ct][reg];
        }
      }
    }
    __syncthreads();
#pragma unroll
    for (int j = 0; j < 4; ++j) {
      int rl = j * 8 + w;          // LDS row, 0..31
      int col = (t & 63) * 4;      // 64 lanes * float4 = 1 KB contiguous
      floatx4 v = *(const floatx4*)&lds[rl][col];
      floatx4 sg;
      sg.x = __builtin_amdgcn_rcpf(1.0f + __expf(-v.x));
      sg.y = __builtin_amdgcn_rcpf(1.0f + __expf(-v.y));
      sg.z = __builtin_amdgcn_rcpf(1.0f + __expf(-v.z));
      sg.w = __builtin_amdgcn_rcpf(1.0f + __expf(-v.w));
      size_t addr = (size_t)(rbase + b * 32 + rl) * N_NODES + cbase + col;
      __builtin_nontemporal_store(sg, (floatx4*)&out[addr]);
    }
    __syncthreads();
  }
}

// ---------------- launch ----------------

extern "C" void kernel_launch(void* const* d_in, const int* in_sizes, int n_in,
                              void* d_out, int out_size, void* d_ws, size_t ws_size,
                              hipStream_t stream) {
  const float* x = (const float*)d_in[0];
  const float* W_l1 = (const float*)d_in[1];
  const float* W_r1 = (const float*)d_in[2];
  const float* b1 = (const float*)d_in[3];
  const float* W_l2 = (const float*)d_in[4];
  const float* W_r2 = (const float*)d_in[5];
  const float* b2 = (const float*)d_in[6];
  const float* W_lin = (const float*)d_in[7];
  const float* b_lin = (const float*)d_in[8];
  const int* edge = (const int*)d_in[9];
  const int* esrc = edge;
  const int* edst = edge + N_EDGES;

  int* deg = (int*)d_ws;
  int* row_ptr = deg + 16384;
  int* cursor = row_ptr + 16448;
  float* deg_inv = (float*)(cursor + 16384);
  int* col_idx = (int*)(deg_inv + 16384);
  float* agg = (float*)(col_idx + N_EDGES);
  float* h = agg + (size_t)N_NODES * 128;
  float* h2 = h + (size_t)N_NODES * 128;
  _Float16* zh = (_Float16*)(h2 + (size_t)N_NODES * 64);

  float* A = (float*)d_out;
  float* z = A + (size_t)N_NODES * N_NODES;
  float* xo = z + (size_t)N_NODES * 64;

  (void)hipMemsetAsync(deg, 0, N_NODES * sizeof(int), stream);
  hist_kernel<<<N_EDGES / 256, 256, 0, stream>>>(edst, deg);
  scan_kernel<<<1, 1024, 0, stream>>>(deg, row_ptr, cursor, deg_inv);
  scatter_kernel<<<N_EDGES / 256, 256, 0, stream>>>(esrc, edst, cursor, col_idx);

  aggregate_kernel<<<N_NODES / 8, 512, 0, stream>>>(x, row_ptr, col_idx, deg_inv, agg);
  sage_gemm_kernel<128, 32><<<N_NODES / 32, 256, 0, stream>>>(agg, x, W_l1, W_r1, b1, h);
  aggregate_kernel<<<N_NODES / 8, 512, 0, stream>>>(h, row_ptr, col_idx, deg_inv, agg);
  sage_gemm_kernel<64, 32><<<N_NODES / 32, 256, 0, stream>>>(agg, h, W_l2, W_r2, b2, h2);
  normalize_kernel<<<N_NODES / 4, 256, 0, stream>>>(h2, z, zh);
  lin_elu_kernel<<<N_NODES / 32, 256, 0, stream>>>(z, W_lin, b_lin, xo);

  dim3 grid(N_NODES / 256, N_NODES / 128);
  apred_kernel<<<grid, 512, 0, stream>>>(zh, A);
}

// Round 4
// 342.401 us; speedup vs baseline: 1.1646x; 1.0281x over previous
//
#include <hip/hip_runtime.h>

#define N_NODES 16384
#define N_EDGES 524288

typedef _Float16 half8 __attribute__((ext_vector_type(8)));
typedef _Float16 half4 __attribute__((ext_vector_type(4)));
typedef float floatx16 __attribute__((ext_vector_type(16)));
typedef float floatx4 __attribute__((ext_vector_type(4)));

// ---------------- CSR build ----------------

__global__ __launch_bounds__(256) void hist_kernel(const int* __restrict__ dst,
                                                   int* __restrict__ deg) {
  int e = blockIdx.x * 256 + threadIdx.x;
  atomicAdd(&deg[dst[e]], 1);
}

__global__ __launch_bounds__(1024) void scan_kernel(const int* __restrict__ deg,
                                                    int* __restrict__ row_ptr,
                                                    int* __restrict__ cursor,
                                                    float* __restrict__ deg_inv) {
  __shared__ int part[1024];
  int t = threadIdx.x;
  int base = t * 16;
  int loc[16];
  int s = 0;
#pragma unroll
  for (int i = 0; i < 16; ++i) { loc[i] = deg[base + i]; s += loc[i]; }
  part[t] = s;
  __syncthreads();
  for (int off = 1; off < 1024; off <<= 1) {
    int v = (t >= off) ? part[t - off] : 0;
    __syncthreads();
    part[t] += v;
    __syncthreads();
  }
  int run = (t == 0) ? 0 : part[t - 1];
#pragma unroll
  for (int i = 0; i < 16; ++i) {
    row_ptr[base + i] = run;
    cursor[base + i] = run;
    int d = loc[i];
    deg_inv[base + i] = 1.0f / (float)(d > 0 ? d : 1);
    run += d;
  }
  if (t == 1023) row_ptr[N_NODES] = run;
}

__global__ __launch_bounds__(256) void scatter_kernel(const int* __restrict__ src,
                                                      const int* __restrict__ dst,
                                                      int* __restrict__ cursor,
                                                      int* __restrict__ col_idx) {
  int e = blockIdx.x * 256 + threadIdx.x;
  int d = dst[e];
  int pos = atomicAdd(&cursor[d], 1);
  col_idx[pos] = src[e];
}

// ---------------- mean aggregation v3: float4 gathers, 2 edges per load instr ----------
// Lanes 0-31 handle even edge of each pair (float4 = feature group fl*4), lanes
// 32-63 the odd edge; __shfl_xor(,32) combines. Halves load+shfl issue count vs v2.

__global__ __launch_bounds__(512) void aggregate_kernel(const float* __restrict__ feat,
                                                        const int* __restrict__ row_ptr,
                                                        const int* __restrict__ col_idx,
                                                        const float* __restrict__ deg_inv,
                                                        float* __restrict__ out) {
  int node = blockIdx.x * 8 + (threadIdx.x >> 6);
  int lane = threadIdx.x & 63;
  int half = lane >> 5;
  int fl = lane & 31;
  int beg = row_ptr[node], end = row_ptr[node + 1];
  float ax = 0.f, ay = 0.f, az = 0.f, aw = 0.f;
  for (int base = beg; base < end; base += 64) {
    int rem = end - base;
    int cnt = rem < 64 ? rem : 64;
    int idx = (lane < cnt) ? col_idx[base + lane] : 0;
    int j = 0;
    for (; j + 8 <= cnt; j += 8) {
      int s0 = __shfl(idx, j + half);
      int s1 = __shfl(idx, j + 2 + half);
      int s2 = __shfl(idx, j + 4 + half);
      int s3 = __shfl(idx, j + 6 + half);
      float4 v0 = *(const float4*)&feat[(size_t)s0 * 128 + fl * 4];
      float4 v1 = *(const float4*)&feat[(size_t)s1 * 128 + fl * 4];
      float4 v2 = *(const float4*)&feat[(size_t)s2 * 128 + fl * 4];
      float4 v3 = *(const float4*)&feat[(size_t)s3 * 128 + fl * 4];
      ax += v0.x + v1.x + v2.x + v3.x;
      ay += v0.y + v1.y + v2.y + v3.y;
      az += v0.z + v1.z + v2.z + v3.z;
      aw += v0.w + v1.w + v2.w + v3.w;
    }
    for (; j + 2 <= cnt; j += 2) {
      int s0 = __shfl(idx, j + half);
      float4 v0 = *(const float4*)&feat[(size_t)s0 * 128 + fl * 4];
      ax += v0.x; ay += v0.y; az += v0.z; aw += v0.w;
    }
    if (j < cnt) {
      int s0 = __shfl(idx, j);
      if (half == 0) {
        float4 v0 = *(const float4*)&feat[(size_t)s0 * 128 + fl * 4];
        ax += v0.x; ay += v0.y; az += v0.z; aw += v0.w;
      }
    }
  }
  ax += __shfl_xor(ax, 32);
  ay += __shfl_xor(ay, 32);
  az += __shfl_xor(az, 32);
  aw += __shfl_xor(aw, 32);
  if (half == 0) {
    float inv = deg_inv[node];
    float4 r;
    r.x = ax * inv; r.y = ay * inv; r.z = az * inv; r.w = aw * inv;
    *(float4*)&out[(size_t)node * 128 + fl * 4] = r;
  }
}

// ---------------- SAGE layer 1: h = aggr@Wl + self@Wr + b (f32 FMA) ----------------

__global__ __launch_bounds__(256) void sage1_kernel(const float* __restrict__ aggr,
                                                    const float* __restrict__ self,
                                                    const float* __restrict__ Wl,
                                                    const float* __restrict__ Wr,
                                                    const float* __restrict__ bias,
                                                    float* __restrict__ out) {
  constexpr int OUTC = 128, ROWS = 32, CG = 32, RG = 8, RPT = 4;
  __shared__ float l1[ROWS][129];
  __shared__ float l2[ROWS][129];
  int t = threadIdx.x;
  size_t row0 = (size_t)blockIdx.x * ROWS;
  for (int i = t; i < ROWS * 128; i += 256) {
    int r = i >> 7, c = i & 127;
    l1[r][c] = aggr[(row0 + r) * 128 + c];
    l2[r][c] = self[(row0 + r) * 128 + c];
  }
  __syncthreads();
  int c0 = (t % CG) * 4;
  int r0 = (t / CG) * RPT;
  float acc[RPT][4] = {};
#pragma unroll 4
  for (int k = 0; k < 128; ++k) {
    float4 wl = *(const float4*)&Wl[k * OUTC + c0];
    float4 wr = *(const float4*)&Wr[k * OUTC + c0];
#pragma unroll
    for (int r = 0; r < RPT; ++r) {
      float a = l1[r0 + r][k];
      float b = l2[r0 + r][k];
      acc[r][0] += a * wl.x + b * wr.x;
      acc[r][1] += a * wl.y + b * wr.y;
      acc[r][2] += a * wl.z + b * wr.z;
      acc[r][3] += a * wl.w + b * wr.w;
    }
  }
  float4 bv = *(const float4*)&bias[c0];
#pragma unroll
  for (int r = 0; r < RPT; ++r) {
    float4 o;
    o.x = acc[r][0] + bv.x;
    o.y = acc[r][1] + bv.y;
    o.z = acc[r][2] + bv.z;
    o.w = acc[r][3] + bv.w;
    *(float4*)&out[(row0 + r0 + r) * OUTC + c0] = o;
  }
}

// ---------------- fused: SAGE layer 2 + row-normalize + lin_elu ----------------
// Block owns 32 full rows: h2 (32x64) -> per-row L2 norm -> z,zh -> x_ = elu(z@W_lin+b).

__global__ __launch_bounds__(256) void sage2_fused_kernel(const float* __restrict__ aggr,
                                                          const float* __restrict__ self,
                                                          const float* __restrict__ Wl,
                                                          const float* __restrict__ Wr,
                                                          const float* __restrict__ bias,
                                                          const float* __restrict__ W_lin,
                                                          const float* __restrict__ b_lin,
                                                          float* __restrict__ z,
                                                          _Float16* __restrict__ zh,
                                                          float* __restrict__ xo) {
  constexpr int OUTC = 64, ROWS = 32, CG = 16, RPT = 2;
  __shared__ float l1[ROWS][129];
  __shared__ float l2[ROWS][129];
  __shared__ float part[ROWS][CG + 1];
  __shared__ float rinv[ROWS];
  int t = threadIdx.x;
  size_t row0 = (size_t)blockIdx.x * ROWS;
  for (int i = t; i < ROWS * 128; i += 256) {
    int r = i >> 7, c = i & 127;
    l1[r][c] = aggr[(row0 + r) * 128 + c];
    l2[r][c] = self[(row0 + r) * 128 + c];
  }
  __syncthreads();
  int c0 = (t % CG) * 4;
  int r0 = (t / CG) * RPT;
  float acc[RPT][4] = {};
#pragma unroll 4
  for (int k = 0; k < 128; ++k) {
    float4 wl = *(const float4*)&Wl[k * OUTC + c0];
    float4 wr = *(const float4*)&Wr[k * OUTC + c0];
#pragma unroll
    for (int r = 0; r < RPT; ++r) {
      float a = l1[r0 + r][k];
      float b = l2[r0 + r][k];
      acc[r][0] += a * wl.x + b * wr.x;
      acc[r][1] += a * wl.y + b * wr.y;
      acc[r][2] += a * wl.z + b * wr.z;
      acc[r][3] += a * wl.w + b * wr.w;
    }
  }
  float4 bv = *(const float4*)&bias[c0];
#pragma unroll
  for (int r = 0; r < RPT; ++r) {
    acc[r][0] += bv.x; acc[r][1] += bv.y; acc[r][2] += bv.z; acc[r][3] += bv.w;
    part[r0 + r][t % CG] = acc[r][0] * acc[r][0] + acc[r][1] * acc[r][1] +
                           acc[r][2] * acc[r][2] + acc[r][3] * acc[r][3];
  }
  __syncthreads();   // k-loop reads of l1/l2 done; partials visible
  if (t < ROWS) {
    float s = 0.f;
#pragma unroll
    for (int i = 0; i < CG; ++i) s += part[t][i];
    rinv[t] = 1.0f / fmaxf(sqrtf(s), 1e-12f);
  }
  __syncthreads();   // rinv visible; safe to overwrite l1 (all past k-loop)
#pragma unroll
  for (int r = 0; r < RPT; ++r) {
    float inv = rinv[r0 + r];
    float4 o;
    o.x = acc[r][0] * inv; o.y = acc[r][1] * inv;
    o.z = acc[r][2] * inv; o.w = acc[r][3] * inv;
    *(float4*)&z[(row0 + r0 + r) * 64 + c0] = o;
    half4 hv;
    hv.x = (_Float16)o.x; hv.y = (_Float16)o.y;
    hv.z = (_Float16)o.z; hv.w = (_Float16)o.w;
    *(half4*)&zh[(row0 + r0 + r) * 64 + c0] = hv;
    l1[r0 + r][c0] = o.x; l1[r0 + r][c0 + 1] = o.y;
    l1[r0 + r][c0 + 2] = o.z; l1[r0 + r][c0 + 3] = o.w;
  }
  __syncthreads();   // staged z visible
  // x_ = elu(z @ W_lin + b_lin): 32 rows x 128 cols
  int cc = (t & 31) * 4;
  int rr = (t >> 5) * 4;
  float a2[4][4] = {};
#pragma unroll 4
  for (int k = 0; k < 64; ++k) {
    float4 w = *(const float4*)&W_lin[k * 128 + cc];
#pragma unroll
    for (int r = 0; r < 4; ++r) {
      float a = l1[rr + r][k];
      a2[r][0] += a * w.x;
      a2[r][1] += a * w.y;
      a2[r][2] += a * w.z;
      a2[r][3] += a * w.w;
    }
  }
  float4 bl = *(const float4*)&b_lin[cc];
#pragma unroll
  for (int r = 0; r < 4; ++r) {
    float v0 = a2[r][0] + bl.x;
    float v1 = a2[r][1] + bl.y;
    float v2 = a2[r][2] + bl.z;
    float v3 = a2[r][3] + bl.w;
    float4 o;
    o.x = v0 > 0.f ? v0 : expm1f(v0);
    o.y = v1 > 0.f ? v1 : expm1f(v1);
    o.z = v2 > 0.f ? v2 : expm1f(v2);
    o.w = v3 > 0.f ? v3 : expm1f(v3);
    *(float4*)&xo[(row0 + rr + r) * 128 + cc] = o;
  }
}

// ---------------- A_pred = sigmoid(z z^T), f16 MFMA, 2-phase LDS epilogue ----------
// Block: 128x256, 8 waves (2x4), wave = 64x64 via 2x2 MFMA 32x32x16.
// Epilogue: 2 phases; in each, ALL waves stage one 32-row band pair into a
// 64 KB LDS double-slab, then everyone stores 64 KB as 1 KB contiguous
// nontemporal wave stores. 3 barriers/block total.

__global__ __launch_bounds__(512, 4) void apred_kernel(const _Float16* __restrict__ zh,
                                                       float* __restrict__ out) {
  __shared__ float lds[2][32][256];
  int t = threadIdx.x;
  int lane = t & 63;
  int w = t >> 6;
  int wr = w >> 2, wc = w & 3;
  int lmod = lane & 31, lhalf = lane >> 5;
  int rbase = blockIdx.y * 128;
  int cbase = blockIdx.x * 256;
  int rw = rbase + wr * 64;
  int cw = cbase + wc * 64;

  floatx16 acc[2][2] = {};
#pragma unroll
  for (int kc = 0; kc < 4; ++kc) {
    int ko = kc * 16 + lhalf * 8;
    half8 a0 = *(const half8*)&zh[(size_t)(rw + lmod) * 64 + ko];
    half8 a1 = *(const half8*)&zh[(size_t)(rw + 32 + lmod) * 64 + ko];
    half8 b0 = *(const half8*)&zh[(size_t)(cw + lmod) * 64 + ko];
    half8 b1 = *(const half8*)&zh[(size_t)(cw + 32 + lmod) * 64 + ko];
    acc[0][0] = __builtin_amdgcn_mfma_f32_32x32x16_f16(a0, b0, acc[0][0], 0, 0, 0);
    acc[0][1] = __builtin_amdgcn_mfma_f32_32x32x16_f16(a0, b1, acc[0][1], 0, 0, 0);
    acc[1][0] = __builtin_amdgcn_mfma_f32_32x32x16_f16(a1, b0, acc[1][0], 0, 0, 0);
    acc[1][1] = __builtin_amdgcn_mfma_f32_32x32x16_f16(a1, b1, acc[1][1], 0, 0, 0);
  }

#pragma unroll
  for (int p = 0; p < 2; ++p) {
    if (p) __syncthreads();   // previous phase's LDS reads done
#pragma unroll
    for (int ct = 0; ct < 2; ++ct) {
#pragma unroll
      for (int reg = 0; reg < 16; ++reg) {
        int r = (reg & 3) + 8 * (reg >> 2) + 4 * lhalf;
        lds[wr][r][wc * 64 + ct * 32 + lmod] = acc[p][ct][reg];
      }
    }
    __syncthreads();
#pragma unroll
    for (int s = 0; s < 2; ++s) {
#pragma unroll
      for (int j = 0; j < 4; ++j) {
        int rl = j * 8 + w;
        floatx4 v = *(const floatx4*)&lds[s][rl][lane * 4];
        floatx4 sg;
        sg.x = __builtin_amdgcn_rcpf(1.0f + __expf(-v.x));
        sg.y = __builtin_amdgcn_rcpf(1.0f + __expf(-v.y));
        sg.z = __builtin_amdgcn_rcpf(1.0f + __expf(-v.z));
        sg.w = __builtin_amdgcn_rcpf(1.0f + __expf(-v.w));
        size_t addr = (size_t)(rbase + s * 64 + p * 32 + rl) * N_NODES + cbase + lane * 4;
        __builtin_nontemporal_store(sg, (floatx4*)&out[addr]);
      }
    }
  }
}

// ---------------- launch ----------------

extern "C" void kernel_launch(void* const* d_in, const int* in_sizes, int n_in,
                              void* d_out, int out_size, void* d_ws, size_t ws_size,
                              hipStream_t stream) {
  const float* x = (const float*)d_in[0];
  const float* W_l1 = (const float*)d_in[1];
  const float* W_r1 = (const float*)d_in[2];
  const float* b1 = (const float*)d_in[3];
  const float* W_l2 = (const float*)d_in[4];
  const float* W_r2 = (const float*)d_in[5];
  const float* b2 = (const float*)d_in[6];
  const float* W_lin = (const float*)d_in[7];
  const float* b_lin = (const float*)d_in[8];
  const int* edge = (const int*)d_in[9];
  const int* esrc = edge;
  const int* edst = edge + N_EDGES;

  int* deg = (int*)d_ws;
  int* row_ptr = deg + 16384;
  int* cursor = row_ptr + 16448;
  float* deg_inv = (float*)(cursor + 16384);
  int* col_idx = (int*)(deg_inv + 16384);
  float* agg = (float*)(col_idx + N_EDGES);
  float* h = agg + (size_t)N_NODES * 128;
  _Float16* zh = (_Float16*)(h + (size_t)N_NODES * 128);

  float* A = (float*)d_out;
  float* z = A + (size_t)N_NODES * N_NODES;
  float* xo = z + (size_t)N_NODES * 64;

  (void)hipMemsetAsync(deg, 0, N_NODES * sizeof(int), stream);
  hist_kernel<<<N_EDGES / 256, 256, 0, stream>>>(edst, deg);
  scan_kernel<<<1, 1024, 0, stream>>>(deg, row_ptr, cursor, deg_inv);
  scatter_kernel<<<N_EDGES / 256, 256, 0, stream>>>(esrc, edst, cursor, col_idx);

  aggregate_kernel<<<N_NODES / 8, 512, 0, stream>>>(x, row_ptr, col_idx, deg_inv, agg);
  sage1_kernel<<<N_NODES / 32, 256, 0, stream>>>(agg, x, W_l1, W_r1, b1, h);
  aggregate_kernel<<<N_NODES / 8, 512, 0, stream>>>(h, row_ptr, col_idx, deg_inv, agg);
  sage2_fused_kernel<<<N_NODES / 32, 256, 0, stream>>>(agg, h, W_l2, W_r2, b2,
                                                       W_lin, b_lin, z, zh, xo);

  dim3 grid(N_NODES / 256, N_NODES / 128);
  apred_kernel<<<grid, 512, 0, stream>>>(zh, A);
}

// Round 5
// 308.953 us; speedup vs baseline: 1.2907x; 1.1083x over previous
//
#include <hip/hip_runtime.h>

#define N_NODES 16384
#define N_EDGES 524288

typedef _Float16 half8v __attribute__((ext_vector_type(8)));
typedef _Float16 half4v __attribute__((ext_vector_type(4)));
typedef float floatx16 __attribute__((ext_vector_type(16)));
typedef float floatx4 __attribute__((ext_vector_type(4)));

#define MFMA16(a, b, c) __builtin_amdgcn_mfma_f32_32x32x16_f16(a, b, c, 0, 0, 0)

// ---------------- CSR build ----------------

__global__ __launch_bounds__(256) void hist_kernel(const int* __restrict__ dst,
                                                   int* __restrict__ deg) {
  int e = blockIdx.x * 256 + threadIdx.x;
  atomicAdd(&deg[dst[e]], 1);
}

__global__ __launch_bounds__(1024) void scan_kernel(const int* __restrict__ deg,
                                                    int* __restrict__ row_ptr,
                                                    int* __restrict__ cursor,
                                                    float* __restrict__ deg_inv) {
  __shared__ int part[1024];
  int t = threadIdx.x;
  int base = t * 16;
  int loc[16];
  int s = 0;
#pragma unroll
  for (int i = 0; i < 16; ++i) { loc[i] = deg[base + i]; s += loc[i]; }
  part[t] = s;
  __syncthreads();
  for (int off = 1; off < 1024; off <<= 1) {
    int v = (t >= off) ? part[t - off] : 0;
    __syncthreads();
    part[t] += v;
    __syncthreads();
  }
  int run = (t == 0) ? 0 : part[t - 1];
#pragma unroll
  for (int i = 0; i < 16; ++i) {
    row_ptr[base + i] = run;
    cursor[base + i] = run;
    int d = loc[i];
    deg_inv[base + i] = 1.0f / (float)(d > 0 ? d : 1);
    run += d;
  }
  if (t == 1023) row_ptr[N_NODES] = run;
}

__global__ __launch_bounds__(256) void scatter_kernel(const int* __restrict__ src,
                                                      const int* __restrict__ dst,
                                                      int* __restrict__ cursor,
                                                      int* __restrict__ col_idx) {
  int e = blockIdx.x * 256 + threadIdx.x;
  int d = dst[e];
  int pos = atomicAdd(&cursor[d], 1);
  col_idx[pos] = src[e];
}

// ---------------- prep: x -> f16, weights -> transposed f16 ----------------

__global__ __launch_bounds__(256) void prep_kernel(const float* __restrict__ x,
                                                   _Float16* __restrict__ xh,
                                                   const float* __restrict__ Wl1,
                                                   const float* __restrict__ Wr1,
                                                   const float* __restrict__ Wl2,
                                                   const float* __restrict__ Wr2,
                                                   const float* __restrict__ Wlin,
                                                   _Float16* __restrict__ Wl1t,
                                                   _Float16* __restrict__ Wr1t,
                                                   _Float16* __restrict__ Wl2t,
                                                   _Float16* __restrict__ Wr2t,
                                                   _Float16* __restrict__ Wlint) {
  int b = blockIdx.x, t = threadIdx.x;
  if (b < 1024) {
    size_t base = (size_t)b * 2048 + t * 8;
    float4 v0 = *(const float4*)&x[base];
    float4 v1 = *(const float4*)&x[base + 4];
    half8v h;
    h[0] = (_Float16)v0.x; h[1] = (_Float16)v0.y;
    h[2] = (_Float16)v0.z; h[3] = (_Float16)v0.w;
    h[4] = (_Float16)v1.x; h[5] = (_Float16)v1.y;
    h[6] = (_Float16)v1.z; h[7] = (_Float16)v1.w;
    *(half8v*)&xh[base] = h;
  } else {
    int m = b - 1024;
    const float* W; _Float16* Wt; int K, C;
    if (m == 0)      { W = Wl1;  Wt = Wl1t;  K = 128; C = 128; }
    else if (m == 1) { W = Wr1;  Wt = Wr1t;  K = 128; C = 128; }
    else if (m == 2) { W = Wl2;  Wt = Wl2t;  K = 128; C = 64;  }
    else if (m == 3) { W = Wr2;  Wt = Wr2t;  K = 128; C = 64;  }
    else             { W = Wlin; Wt = Wlint; K = 64;  C = 128; }
    int sh = (C == 128) ? 7 : 6;
    for (int i = t; i < K * C; i += 256) {
      int k = i >> sh, c = i & (C - 1);
      Wt[c * K + k] = (_Float16)W[i];
    }
  }
}

// ---------------- mean aggregation v4: f16 rows (256 B), 4 edges per wave-load ----------
// 16-lane groups g=lane>>4 each own one edge per step; lane fl=lane&15 covers
// features fl*8..fl*8+7 as half8. f32 accumulate; cross-group combine via shfl_xor.

__global__ __launch_bounds__(512) void aggregate_f16_kernel(const _Float16* __restrict__ feat,
                                                            const int* __restrict__ row_ptr,
                                                            const int* __restrict__ col_idx,
                                                            const float* __restrict__ deg_inv,
                                                            _Float16* __restrict__ out) {
  int node = blockIdx.x * 8 + (threadIdx.x >> 6);
  int lane = threadIdx.x & 63;
  int g = lane >> 4, fl = lane & 15;
  int beg = row_ptr[node], end = row_ptr[node + 1];
  float acc[8] = {};
  for (int base = beg; base < end; base += 64) {
    int rem = end - base;
    int cnt = rem < 64 ? rem : 64;
    int idx = (lane < cnt) ? col_idx[base + lane] : 0;
    int jmain = cnt & ~15;
    for (int j = 0; j < jmain; j += 16) {
#pragma unroll
      for (int u = 0; u < 4; ++u) {
        int s = __shfl(idx, j + u * 4 + g);
        half8v v = *(const half8v*)&feat[(size_t)s * 128 + fl * 8];
#pragma unroll
        for (int i = 0; i < 8; ++i) acc[i] += (float)v[i];
      }
    }
    for (int j = jmain; j < cnt; j += 4) {
      int s = __shfl(idx, j + g);
      if (j + g < cnt) {
        half8v v = *(const half8v*)&feat[(size_t)s * 128 + fl * 8];
#pragma unroll
        for (int i = 0; i < 8; ++i) acc[i] += (float)v[i];
      }
    }
  }
#pragma unroll
  for (int i = 0; i < 8; ++i) {
    acc[i] += __shfl_xor(acc[i], 16);
    acc[i] += __shfl_xor(acc[i], 32);
  }
  if (g == 0) {
    float inv = deg_inv[node];
    half8v r;
#pragma unroll
    for (int i = 0; i < 8; ++i) r[i] = (_Float16)(acc[i] * inv);
    *(half8v*)&out[(size_t)node * 128 + fl * 8] = r;
  }
}

// ---------------- SAGE layer 1 (MFMA): hh = f16(aggr@Wl1 + x@Wr1 + b1) ----------------
// Block 64 rows x 128 cols, 4 waves (2 row x 2 col); wave = 32x64 = 2 MFMA col-tiles.
// Operand frags straight from global (L2-resident); C-layout: col=lane&31,
// row=(reg&3)+8*(reg>>2)+4*(lane>>5).

__global__ __launch_bounds__(256) void sage1_mfma_kernel(const _Float16* __restrict__ aggr,
                                                         const _Float16* __restrict__ self,
                                                         const _Float16* __restrict__ Wlt,
                                                         const _Float16* __restrict__ Wrt,
                                                         const float* __restrict__ bias,
                                                         _Float16* __restrict__ hh) {
  int t = threadIdx.x;
  int lane = t & 63, w = t >> 6;
  int wr = w >> 1, wc = w & 1;
  int lmod = lane & 31, lhalf = lane >> 5;
  int row0 = blockIdx.x * 64 + wr * 32;
  int c0 = wc * 64;
  floatx16 acc[2] = {};
#pragma unroll
  for (int kc = 0; kc < 8; ++kc) {
    int ko = kc * 16 + lhalf * 8;
    half8v a = *(const half8v*)&aggr[(size_t)(row0 + lmod) * 128 + ko];
    half8v b0 = *(const half8v*)&Wlt[(size_t)(c0 + lmod) * 128 + ko];
    half8v b1 = *(const half8v*)&Wlt[(size_t)(c0 + 32 + lmod) * 128 + ko];
    acc[0] = MFMA16(a, b0, acc[0]);
    acc[1] = MFMA16(a, b1, acc[1]);
  }
#pragma unroll
  for (int kc = 0; kc < 8; ++kc) {
    int ko = kc * 16 + lhalf * 8;
    half8v a = *(const half8v*)&self[(size_t)(row0 + lmod) * 128 + ko];
    half8v b0 = *(const half8v*)&Wrt[(size_t)(c0 + lmod) * 128 + ko];
    half8v b1 = *(const half8v*)&Wrt[(size_t)(c0 + 32 + lmod) * 128 + ko];
    acc[0] = MFMA16(a, b0, acc[0]);
    acc[1] = MFMA16(a, b1, acc[1]);
  }
#pragma unroll
  for (int ct = 0; ct < 2; ++ct) {
    float bv = bias[c0 + ct * 32 + lmod];
#pragma unroll
    for (int reg = 0; reg < 16; ++reg) {
      int r = (reg & 3) + 8 * (reg >> 2) + 4 * lhalf;
      hh[(size_t)(row0 + r) * 128 + c0 + ct * 32 + lmod] = (_Float16)(acc[ct][reg] + bv);
    }
  }
}

// ---------------- fused SAGE layer 2 + normalize + lin_elu (MFMA) ----------------
// Block 64 rows; phase 1: h2 = aggr@Wl2 + hh@Wr2 + b2 into LDS (f32, stride 65 =
// conflict-free scalar access). Phase 2: per-row rsqrt norm. Phase 3: normalize
// in place + store z (f32) and zh (f16). Phase 4: x_ = elu(z@W_lin + b_lin) via
// MFMA, A-frags rebuilt from LDS scalars.

__global__ __launch_bounds__(256) void sage2_fused_kernel(const _Float16* __restrict__ aggr,
                                                          const _Float16* __restrict__ self,
                                                          const _Float16* __restrict__ Wlt,
                                                          const _Float16* __restrict__ Wrt,
                                                          const float* __restrict__ bias,
                                                          const _Float16* __restrict__ Wlint,
                                                          const float* __restrict__ b_lin,
                                                          float* __restrict__ z,
                                                          _Float16* __restrict__ zh,
                                                          float* __restrict__ xo) {
  __shared__ float lds2[64][65];
  __shared__ float rinv[64];
  int t = threadIdx.x;
  int lane = t & 63, w = t >> 6;
  int wr = w >> 1, wc = w & 1;
  int lmod = lane & 31, lhalf = lane >> 5;
  int rowb = blockIdx.x * 64;
  int row0 = rowb + wr * 32;
  int c0 = wc * 32;

  floatx16 acc = {};
#pragma unroll
  for (int kc = 0; kc < 8; ++kc) {
    int ko = kc * 16 + lhalf * 8;
    half8v a = *(const half8v*)&aggr[(size_t)(row0 + lmod) * 128 + ko];
    half8v b = *(const half8v*)&Wlt[(size_t)(c0 + lmod) * 128 + ko];
    acc = MFMA16(a, b, acc);
  }
#pragma unroll
  for (int kc = 0; kc < 8; ++kc) {
    int ko = kc * 16 + lhalf * 8;
    half8v a = *(const half8v*)&self[(size_t)(row0 + lmod) * 128 + ko];
    half8v b = *(const half8v*)&Wrt[(size_t)(c0 + lmod) * 128 + ko];
    acc = MFMA16(a, b, acc);
  }
  float bv = bias[c0 + lmod];
#pragma unroll
  for (int reg = 0; reg < 16; ++reg) {
    int r = (reg & 3) + 8 * (reg >> 2) + 4 * lhalf;
    lds2[wr * 32 + r][c0 + lmod] = acc[reg] + bv;
  }
  __syncthreads();
  if (t < 64) {
    float s = 0.f;
#pragma unroll 16
    for (int i = 0; i < 64; ++i) { float v = lds2[t][i]; s += v * v; }
    rinv[t] = 1.0f / fmaxf(sqrtf(s), 1e-12f);
  }
  __syncthreads();
  {
    int row = t >> 2;
    int cb = (t & 3) * 16;
    float inv = rinv[row];
#pragma unroll
    for (int q = 0; q < 4; ++q) {
      int c = cb + q * 4;
      float o0 = lds2[row][c] * inv;
      float o1 = lds2[row][c + 1] * inv;
      float o2 = lds2[row][c + 2] * inv;
      float o3 = lds2[row][c + 3] * inv;
      lds2[row][c] = o0; lds2[row][c + 1] = o1;
      lds2[row][c + 2] = o2; lds2[row][c + 3] = o3;
      float4 zo; zo.x = o0; zo.y = o1; zo.z = o2; zo.w = o3;
      *(float4*)&z[(size_t)(rowb + row) * 64 + c] = zo;
      half4v hv;
      hv[0] = (_Float16)o0; hv[1] = (_Float16)o1;
      hv[2] = (_Float16)o2; hv[3] = (_Float16)o3;
      *(half4v*)&zh[(size_t)(rowb + row) * 64 + c] = hv;
    }
  }
  __syncthreads();
  // x_ = elu(z @ W_lin + b_lin): wave w owns cols w*32..+32, both 32-row groups
  floatx16 acc2[2] = {};
#pragma unroll
  for (int kc = 0; kc < 4; ++kc) {
    half8v a0, a1;
#pragma unroll
    for (int i = 0; i < 8; ++i) {
      int k = kc * 16 + lhalf * 8 + i;
      a0[i] = (_Float16)lds2[lmod][k];
      a1[i] = (_Float16)lds2[32 + lmod][k];
    }
    half8v b = *(const half8v*)&Wlint[(size_t)(w * 32 + lmod) * 64 + kc * 16 + lhalf * 8];
    acc2[0] = MFMA16(a0, b, acc2[0]);
    acc2[1] = MFMA16(a1, b, acc2[1]);
  }
  float blv = b_lin[w * 32 + lmod];
#pragma unroll
  for (int rg = 0; rg < 2; ++rg) {
#pragma unroll
    for (int reg = 0; reg < 16; ++reg) {
      int r = rg * 32 + (reg & 3) + 8 * (reg >> 2) + 4 * lhalf;
      float v = acc2[rg][reg] + blv;
      v = v > 0.f ? v : expm1f(v);
      xo[(size_t)(rowb + r) * 128 + w * 32 + lmod] = v;
    }
  }
}

// ---------------- A_pred = sigmoid(z z^T), f16 MFMA, 2-phase LDS epilogue ----------

__global__ __launch_bounds__(512, 4) void apred_kernel(const _Float16* __restrict__ zh,
                                                       float* __restrict__ out) {
  __shared__ float lds[2][32][256];
  int t = threadIdx.x;
  int lane = t & 63;
  int w = t >> 6;
  int wr = w >> 2, wc = w & 3;
  int lmod = lane & 31, lhalf = lane >> 5;
  int rbase = blockIdx.y * 128;
  int cbase = blockIdx.x * 256;
  int rw = rbase + wr * 64;
  int cw = cbase + wc * 64;

  floatx16 acc[2][2] = {};
#pragma unroll
  for (int kc = 0; kc < 4; ++kc) {
    int ko = kc * 16 + lhalf * 8;
    half8v a0 = *(const half8v*)&zh[(size_t)(rw + lmod) * 64 + ko];
    half8v a1 = *(const half8v*)&zh[(size_t)(rw + 32 + lmod) * 64 + ko];
    half8v b0 = *(const half8v*)&zh[(size_t)(cw + lmod) * 64 + ko];
    half8v b1 = *(const half8v*)&zh[(size_t)(cw + 32 + lmod) * 64 + ko];
    acc[0][0] = MFMA16(a0, b0, acc[0][0]);
    acc[0][1] = MFMA16(a0, b1, acc[0][1]);
    acc[1][0] = MFMA16(a1, b0, acc[1][0]);
    acc[1][1] = MFMA16(a1, b1, acc[1][1]);
  }

#pragma unroll
  for (int p = 0; p < 2; ++p) {
    if (p) __syncthreads();
#pragma unroll
    for (int ct = 0; ct < 2; ++ct) {
#pragma unroll
      for (int reg = 0; reg < 16; ++reg) {
        int r = (reg & 3) + 8 * (reg >> 2) + 4 * lhalf;
        lds[wr][r][wc * 64 + ct * 32 + lmod] = acc[p][ct][reg];
      }
    }
    __syncthreads();
#pragma unroll
    for (int s = 0; s < 2; ++s) {
#pragma unroll
      for (int j = 0; j < 4; ++j) {
        int rl = j * 8 + w;
        floatx4 v = *(const floatx4*)&lds[s][rl][lane * 4];
        floatx4 sg;
        sg.x = __builtin_amdgcn_rcpf(1.0f + __expf(-v.x));
        sg.y = __builtin_amdgcn_rcpf(1.0f + __expf(-v.y));
        sg.z = __builtin_amdgcn_rcpf(1.0f + __expf(-v.z));
        sg.w = __builtin_amdgcn_rcpf(1.0f + __expf(-v.w));
        size_t addr = (size_t)(rbase + s * 64 + p * 32 + rl) * N_NODES + cbase + lane * 4;
        __builtin_nontemporal_store(sg, (floatx4*)&out[addr]);
      }
    }
  }
}

// ---------------- launch ----------------

extern "C" void kernel_launch(void* const* d_in, const int* in_sizes, int n_in,
                              void* d_out, int out_size, void* d_ws, size_t ws_size,
                              hipStream_t stream) {
  const float* x = (const float*)d_in[0];
  const float* W_l1 = (const float*)d_in[1];
  const float* W_r1 = (const float*)d_in[2];
  const float* b1 = (const float*)d_in[3];
  const float* W_l2 = (const float*)d_in[4];
  const float* W_r2 = (const float*)d_in[5];
  const float* b2 = (const float*)d_in[6];
  const float* W_lin = (const float*)d_in[7];
  const float* b_lin = (const float*)d_in[8];
  const int* edge = (const int*)d_in[9];
  const int* esrc = edge;
  const int* edst = edge + N_EDGES;

  int* deg = (int*)d_ws;                                  // 16384
  int* row_ptr = deg + 16384;                             // 16448 (pad)
  int* cursor = row_ptr + 16448;                          // 16384
  float* deg_inv = (float*)(cursor + 16384);              // 16384
  int* col_idx = (int*)(deg_inv + 16384);                 // E
  _Float16* xh = (_Float16*)(col_idx + N_EDGES);          // N*128 f16
  _Float16* hh = xh + (size_t)N_NODES * 128;              // N*128 f16
  _Float16* aggh = hh + (size_t)N_NODES * 128;            // N*128 f16 (reused both layers)
  _Float16* zh = aggh + (size_t)N_NODES * 128;            // N*64 f16
  _Float16* Wl1t = zh + (size_t)N_NODES * 64;             // 16384
  _Float16* Wr1t = Wl1t + 16384;                          // 16384
  _Float16* Wl2t = Wr1t + 16384;                          // 8192
  _Float16* Wr2t = Wl2t + 8192;                           // 8192
  _Float16* Wlint = Wr2t + 8192;                          // 8192

  float* A = (float*)d_out;
  float* z = A + (size_t)N_NODES * N_NODES;
  float* xo = z + (size_t)N_NODES * 64;

  (void)hipMemsetAsync(deg, 0, N_NODES * sizeof(int), stream);
  prep_kernel<<<1029, 256, 0, stream>>>(x, xh, W_l1, W_r1, W_l2, W_r2, W_lin,
                                        Wl1t, Wr1t, Wl2t, Wr2t, Wlint);
  hist_kernel<<<N_EDGES / 256, 256, 0, stream>>>(edst, deg);
  scan_kernel<<<1, 1024, 0, stream>>>(deg, row_ptr, cursor, deg_inv);
  scatter_kernel<<<N_EDGES / 256, 256, 0, stream>>>(esrc, edst, cursor, col_idx);

  aggregate_f16_kernel<<<N_NODES / 8, 512, 0, stream>>>(xh, row_ptr, col_idx, deg_inv, aggh);
  sage1_mfma_kernel<<<N_NODES / 64, 256, 0, stream>>>(aggh, xh, Wl1t, Wr1t, b1, hh);
  aggregate_f16_kernel<<<N_NODES / 8, 512, 0, stream>>>(hh, row_ptr, col_idx, deg_inv, aggh);
  sage2_fused_kernel<<<N_NODES / 64, 256, 0, stream>>>(aggh, hh, Wl2t, Wr2t, b2,
                                                       Wlint, b_lin, z, zh, xo);

  dim3 grid(N_NODES / 256, N_NODES / 128);
  apred_kernel<<<grid, 512, 0, stream>>>(zh, A);
}

// Round 6
// 298.275 us; speedup vs baseline: 1.3369x; 1.0358x over previous
//
#include <hip/hip_runtime.h>

#define N_NODES 16384
#define N_EDGES 524288

typedef _Float16 half8v __attribute__((ext_vector_type(8)));
typedef _Float16 half4v __attribute__((ext_vector_type(4)));
typedef float floatx16 __attribute__((ext_vector_type(16)));
typedef float floatx4 __attribute__((ext_vector_type(4)));

#define MFMA16(a, b, c) __builtin_amdgcn_mfma_f32_32x32x16_f16(a, b, c, 0, 0, 0)

// ---------------- fused CSR-hist + f16 prep ----------------

__global__ __launch_bounds__(256) void hist_prep_kernel(const int* __restrict__ dst,
                                                        int* __restrict__ deg,
                                                        const float* __restrict__ x,
                                                        _Float16* __restrict__ xh,
                                                        const float* __restrict__ Wl1,
                                                        const float* __restrict__ Wr1,
                                                        const float* __restrict__ Wl2,
                                                        const float* __restrict__ Wr2,
                                                        const float* __restrict__ Wlin,
                                                        _Float16* __restrict__ Wl1t,
                                                        _Float16* __restrict__ Wr1t,
                                                        _Float16* __restrict__ Wl2t,
                                                        _Float16* __restrict__ Wr2t,
                                                        _Float16* __restrict__ Wlint) {
  int b = blockIdx.x, t = threadIdx.x;
  if (b < 2048) {
    int e = b * 256 + t;
    atomicAdd(&deg[dst[e]], 1);
  } else if (b < 3072) {
    int bb = b - 2048;
    size_t base = (size_t)bb * 2048 + t * 8;
    float4 v0 = *(const float4*)&x[base];
    float4 v1 = *(const float4*)&x[base + 4];
    half8v h;
    h[0] = (_Float16)v0.x; h[1] = (_Float16)v0.y;
    h[2] = (_Float16)v0.z; h[3] = (_Float16)v0.w;
    h[4] = (_Float16)v1.x; h[5] = (_Float16)v1.y;
    h[6] = (_Float16)v1.z; h[7] = (_Float16)v1.w;
    *(half8v*)&xh[base] = h;
  } else {
    int m = b - 3072;
    const float* W; _Float16* Wt; int K, C;
    if (m == 0)      { W = Wl1;  Wt = Wl1t;  K = 128; C = 128; }
    else if (m == 1) { W = Wr1;  Wt = Wr1t;  K = 128; C = 128; }
    else if (m == 2) { W = Wl2;  Wt = Wl2t;  K = 128; C = 64;  }
    else if (m == 3) { W = Wr2;  Wt = Wr2t;  K = 128; C = 64;  }
    else             { W = Wlin; Wt = Wlint; K = 64;  C = 128; }
    int sh = (C == 128) ? 7 : 6;
    for (int i = t; i < K * C; i += 256) {
      int k = i >> sh, c = i & (C - 1);
      Wt[c * K + k] = (_Float16)W[i];
    }
  }
}

__global__ __launch_bounds__(1024) void scan_kernel(const int* __restrict__ deg,
                                                    int* __restrict__ row_ptr,
                                                    int* __restrict__ cursor,
                                                    float* __restrict__ deg_inv) {
  __shared__ int part[1024];
  int t = threadIdx.x;
  int base = t * 16;
  int loc[16];
  int s = 0;
#pragma unroll
  for (int i = 0; i < 16; ++i) { loc[i] = deg[base + i]; s += loc[i]; }
  part[t] = s;
  __syncthreads();
  for (int off = 1; off < 1024; off <<= 1) {
    int v = (t >= off) ? part[t - off] : 0;
    __syncthreads();
    part[t] += v;
    __syncthreads();
  }
  int run = (t == 0) ? 0 : part[t - 1];
#pragma unroll
  for (int i = 0; i < 16; ++i) {
    row_ptr[base + i] = run;
    cursor[base + i] = run;
    int d = loc[i];
    deg_inv[base + i] = 1.0f / (float)(d > 0 ? d : 1);
    run += d;
  }
  if (t == 1023) row_ptr[N_NODES] = run;
}

__global__ __launch_bounds__(256) void scatter_kernel(const int* __restrict__ src,
                                                      const int* __restrict__ dst,
                                                      int* __restrict__ cursor,
                                                      int* __restrict__ col_idx) {
  int e = blockIdx.x * 256 + threadIdx.x;
  int d = dst[e];
  int pos = atomicAdd(&cursor[d], 1);
  col_idx[pos] = src[e];
}

// ---------------- mean aggregation: f16 rows (256 B), 4 edges per wave-load ----------

__global__ __launch_bounds__(512) void aggregate_f16_kernel(const _Float16* __restrict__ feat,
                                                            const int* __restrict__ row_ptr,
                                                            const int* __restrict__ col_idx,
                                                            const float* __restrict__ deg_inv,
                                                            _Float16* __restrict__ out) {
  int node = blockIdx.x * 8 + (threadIdx.x >> 6);
  int lane = threadIdx.x & 63;
  int g = lane >> 4, fl = lane & 15;
  int beg = row_ptr[node], end = row_ptr[node + 1];
  float acc[8] = {};
  for (int base = beg; base < end; base += 64) {
    int rem = end - base;
    int cnt = rem < 64 ? rem : 64;
    int idx = (lane < cnt) ? col_idx[base + lane] : 0;
    int jmain = cnt & ~15;
    for (int j = 0; j < jmain; j += 16) {
#pragma unroll
      for (int u = 0; u < 4; ++u) {
        int s = __shfl(idx, j + u * 4 + g);
        half8v v = *(const half8v*)&feat[(size_t)s * 128 + fl * 8];
#pragma unroll
        for (int i = 0; i < 8; ++i) acc[i] += (float)v[i];
      }
    }
    for (int j = jmain; j < cnt; j += 4) {
      int s = __shfl(idx, j + g);
      if (j + g < cnt) {
        half8v v = *(const half8v*)&feat[(size_t)s * 128 + fl * 8];
#pragma unroll
        for (int i = 0; i < 8; ++i) acc[i] += (float)v[i];
      }
    }
  }
#pragma unroll
  for (int i = 0; i < 8; ++i) {
    acc[i] += __shfl_xor(acc[i], 16);
    acc[i] += __shfl_xor(acc[i], 32);
  }
  if (g == 0) {
    float inv = deg_inv[node];
    half8v r;
#pragma unroll
    for (int i = 0; i < 8; ++i) r[i] = (_Float16)(acc[i] * inv);
    *(half8v*)&out[(size_t)node * 128 + fl * 8] = r;
  }
}

// ---------------- SAGE layer 1 (MFMA): hh = f16(aggr@Wl1 + x@Wr1 + b1) ----------------

__global__ __launch_bounds__(256) void sage1_mfma_kernel(const _Float16* __restrict__ aggr,
                                                         const _Float16* __restrict__ self,
                                                         const _Float16* __restrict__ Wlt,
                                                         const _Float16* __restrict__ Wrt,
                                                         const float* __restrict__ bias,
                                                         _Float16* __restrict__ hh) {
  int t = threadIdx.x;
  int lane = t & 63, w = t >> 6;
  int wr = w >> 1, wc = w & 1;
  int lmod = lane & 31, lhalf = lane >> 5;
  int row0 = blockIdx.x * 64 + wr * 32;
  int c0 = wc * 64;
  floatx16 acc[2] = {};
#pragma unroll
  for (int kc = 0; kc < 8; ++kc) {
    int ko = kc * 16 + lhalf * 8;
    half8v a = *(const half8v*)&aggr[(size_t)(row0 + lmod) * 128 + ko];
    half8v b0 = *(const half8v*)&Wlt[(size_t)(c0 + lmod) * 128 + ko];
    half8v b1 = *(const half8v*)&Wlt[(size_t)(c0 + 32 + lmod) * 128 + ko];
    acc[0] = MFMA16(a, b0, acc[0]);
    acc[1] = MFMA16(a, b1, acc[1]);
  }
#pragma unroll
  for (int kc = 0; kc < 8; ++kc) {
    int ko = kc * 16 + lhalf * 8;
    half8v a = *(const half8v*)&self[(size_t)(row0 + lmod) * 128 + ko];
    half8v b0 = *(const half8v*)&Wrt[(size_t)(c0 + lmod) * 128 + ko];
    half8v b1 = *(const half8v*)&Wrt[(size_t)(c0 + 32 + lmod) * 128 + ko];
    acc[0] = MFMA16(a, b0, acc[0]);
    acc[1] = MFMA16(a, b1, acc[1]);
  }
#pragma unroll
  for (int ct = 0; ct < 2; ++ct) {
    float bv = bias[c0 + ct * 32 + lmod];
#pragma unroll
    for (int reg = 0; reg < 16; ++reg) {
      int r = (reg & 3) + 8 * (reg >> 2) + 4 * lhalf;
      hh[(size_t)(row0 + r) * 128 + c0 + ct * 32 + lmod] = (_Float16)(acc[ct][reg] + bv);
    }
  }
}

// ---------------- fused SAGE layer 2 + normalize + lin_elu (MFMA) ----------------

__global__ __launch_bounds__(256) void sage2_fused_kernel(const _Float16* __restrict__ aggr,
                                                          const _Float16* __restrict__ self,
                                                          const _Float16* __restrict__ Wlt,
                                                          const _Float16* __restrict__ Wrt,
                                                          const float* __restrict__ bias,
                                                          const _Float16* __restrict__ Wlint,
                                                          const float* __restrict__ b_lin,
                                                          float* __restrict__ z,
                                                          _Float16* __restrict__ zh,
                                                          float* __restrict__ xo) {
  __shared__ float lds2[64][65];
  __shared__ float rinv[64];
  int t = threadIdx.x;
  int lane = t & 63, w = t >> 6;
  int wr = w >> 1, wc = w & 1;
  int lmod = lane & 31, lhalf = lane >> 5;
  int rowb = blockIdx.x * 64;
  int row0 = rowb + wr * 32;
  int c0 = wc * 32;

  floatx16 acc = {};
#pragma unroll
  for (int kc = 0; kc < 8; ++kc) {
    int ko = kc * 16 + lhalf * 8;
    half8v a = *(const half8v*)&aggr[(size_t)(row0 + lmod) * 128 + ko];
    half8v b = *(const half8v*)&Wlt[(size_t)(c0 + lmod) * 128 + ko];
    acc = MFMA16(a, b, acc);
  }
#pragma unroll
  for (int kc = 0; kc < 8; ++kc) {
    int ko = kc * 16 + lhalf * 8;
    half8v a = *(const half8v*)&self[(size_t)(row0 + lmod) * 128 + ko];
    half8v b = *(const half8v*)&Wrt[(size_t)(c0 + lmod) * 128 + ko];
    acc = MFMA16(a, b, acc);
  }
  float bv = bias[c0 + lmod];
#pragma unroll
  for (int reg = 0; reg < 16; ++reg) {
    int r = (reg & 3) + 8 * (reg >> 2) + 4 * lhalf;
    lds2[wr * 32 + r][c0 + lmod] = acc[reg] + bv;
  }
  __syncthreads();
  if (t < 64) {
    float s = 0.f;
#pragma unroll 16
    for (int i = 0; i < 64; ++i) { float v = lds2[t][i]; s += v * v; }
    rinv[t] = 1.0f / fmaxf(sqrtf(s), 1e-12f);
  }
  __syncthreads();
  {
    int row = t >> 2;
    int cb = (t & 3) * 16;
    float inv = rinv[row];
#pragma unroll
    for (int q = 0; q < 4; ++q) {
      int c = cb + q * 4;
      float o0 = lds2[row][c] * inv;
      float o1 = lds2[row][c + 1] * inv;
      float o2 = lds2[row][c + 2] * inv;
      float o3 = lds2[row][c + 3] * inv;
      lds2[row][c] = o0; lds2[row][c + 1] = o1;
      lds2[row][c + 2] = o2; lds2[row][c + 3] = o3;
      float4 zo; zo.x = o0; zo.y = o1; zo.z = o2; zo.w = o3;
      *(float4*)&z[(size_t)(rowb + row) * 64 + c] = zo;
      half4v hv;
      hv[0] = (_Float16)o0; hv[1] = (_Float16)o1;
      hv[2] = (_Float16)o2; hv[3] = (_Float16)o3;
      *(half4v*)&zh[(size_t)(rowb + row) * 64 + c] = hv;
    }
  }
  __syncthreads();
  floatx16 acc2[2] = {};
#pragma unroll
  for (int kc = 0; kc < 4; ++kc) {
    half8v a0, a1;
#pragma unroll
    for (int i = 0; i < 8; ++i) {
      int k = kc * 16 + lhalf * 8 + i;
      a0[i] = (_Float16)lds2[lmod][k];
      a1[i] = (_Float16)lds2[32 + lmod][k];
    }
    half8v b = *(const half8v*)&Wlint[(size_t)(w * 32 + lmod) * 64 + kc * 16 + lhalf * 8];
    acc2[0] = MFMA16(a0, b, acc2[0]);
    acc2[1] = MFMA16(a1, b, acc2[1]);
  }
  float blv = b_lin[w * 32 + lmod];
#pragma unroll
  for (int rg = 0; rg < 2; ++rg) {
#pragma unroll
    for (int reg = 0; reg < 16; ++reg) {
      int r = rg * 32 + (reg & 3) + 8 * (reg >> 2) + 4 * lhalf;
      float v = acc2[rg][reg] + blv;
      v = v > 0.f ? v : expm1f(v);
      xo[(size_t)(rowb + r) * 128 + w * 32 + lmod] = v;
    }
  }
}

// ---------------- A_pred = sigmoid(z z^T), v3: 64x512 blocks, 2 KB row runs ----------
// Block = 8 waves, each one 64x64 tile (2x2 MFMA 32x32x16); block tile = 64 rows
// x 512 cols. Epilogue: 2 bands x {all waves stage 32x512 f32 -> 64 KB LDS,
// barrier, store as 2 KB-per-row contiguous nontemporal runs}. Logical block id
// is row-panel-major (concurrent blocks share rows across adjacent col strips),
// chunked bijectively over 8 XCDs.

__global__ __launch_bounds__(512, 4) void apred_kernel(const _Float16* __restrict__ zh,
                                                       float* __restrict__ out) {
  __shared__ float lds[32][512];
  int t = threadIdx.x;
  int lane = t & 63;
  int w = t >> 6;
  int lmod = lane & 31, lhalf = lane >> 5;
  // chunked XCD swizzle: 8192 blocks, XCD = bid%8 gets logical ids [xcd*1024, ...)
  int bid = blockIdx.x;
  int lid = (bid & 7) * 1024 + (bid >> 3);
  int rbase = (lid >> 5) * 64;        // 256 row panels
  int cbase = (lid & 31) * 512;       // 32 col strips
  int cw = cbase + w * 64;

  floatx16 acc[2][2] = {};
#pragma unroll
  for (int kc = 0; kc < 4; ++kc) {
    int ko = kc * 16 + lhalf * 8;
    half8v a0 = *(const half8v*)&zh[(size_t)(rbase + lmod) * 64 + ko];
    half8v a1 = *(const half8v*)&zh[(size_t)(rbase + 32 + lmod) * 64 + ko];
    half8v b0 = *(const half8v*)&zh[(size_t)(cw + lmod) * 64 + ko];
    half8v b1 = *(const half8v*)&zh[(size_t)(cw + 32 + lmod) * 64 + ko];
    acc[0][0] = MFMA16(a0, b0, acc[0][0]);
    acc[0][1] = MFMA16(a0, b1, acc[0][1]);
    acc[1][0] = MFMA16(a1, b0, acc[1][0]);
    acc[1][1] = MFMA16(a1, b1, acc[1][1]);
  }

#pragma unroll
  for (int band = 0; band < 2; ++band) {
    if (band) __syncthreads();
    // every wave stages its 64-col range of this 32-row band
#pragma unroll
    for (int ct = 0; ct < 2; ++ct) {
#pragma unroll
      for (int reg = 0; reg < 16; ++reg) {
        int r = (reg & 3) + 8 * (reg >> 2) + 4 * lhalf;
        lds[r][w * 64 + ct * 32 + lmod] = acc[band][ct][reg];
      }
    }
    __syncthreads();
    // store 32 rows x 512 cols: 2 waves per row -> 2 KB contiguous runs
#pragma unroll
    for (int j = 0; j < 8; ++j) {
      int row = j * 4 + (w >> 1);
      int col = (w & 1) * 256 + lane * 4;
      floatx4 v = *(const floatx4*)&lds[row][col];
      floatx4 sg;
      sg.x = __builtin_amdgcn_rcpf(1.0f + __expf(-v.x));
      sg.y = __builtin_amdgcn_rcpf(1.0f + __expf(-v.y));
      sg.z = __builtin_amdgcn_rcpf(1.0f + __expf(-v.z));
      sg.w = __builtin_amdgcn_rcpf(1.0f + __expf(-v.w));
      size_t addr = (size_t)(rbase + band * 32 + row) * N_NODES + cbase + col;
      __builtin_nontemporal_store(sg, (floatx4*)&out[addr]);
    }
  }
}

// ---------------- launch ----------------

extern "C" void kernel_launch(void* const* d_in, const int* in_sizes, int n_in,
                              void* d_out, int out_size, void* d_ws, size_t ws_size,
                              hipStream_t stream) {
  const float* x = (const float*)d_in[0];
  const float* W_l1 = (const float*)d_in[1];
  const float* W_r1 = (const float*)d_in[2];
  const float* b1 = (const float*)d_in[3];
  const float* W_l2 = (const float*)d_in[4];
  const float* W_r2 = (const float*)d_in[5];
  const float* b2 = (const float*)d_in[6];
  const float* W_lin = (const float*)d_in[7];
  const float* b_lin = (const float*)d_in[8];
  const int* edge = (const int*)d_in[9];
  const int* esrc = edge;
  const int* edst = edge + N_EDGES;

  int* deg = (int*)d_ws;                                  // 16384
  int* row_ptr = deg + 16384;                             // 16448 (pad)
  int* cursor = row_ptr + 16448;                          // 16384
  float* deg_inv = (float*)(cursor + 16384);              // 16384
  int* col_idx = (int*)(deg_inv + 16384);                 // E
  _Float16* xh = (_Float16*)(col_idx + N_EDGES);          // N*128 f16
  _Float16* hh = xh + (size_t)N_NODES * 128;              // N*128 f16
  _Float16* aggh = hh + (size_t)N_NODES * 128;            // N*128 f16
  _Float16* zh = aggh + (size_t)N_NODES * 128;            // N*64 f16
  _Float16* Wl1t = zh + (size_t)N_NODES * 64;             // 16384
  _Float16* Wr1t = Wl1t + 16384;                          // 16384
  _Float16* Wl2t = Wr1t + 16384;                          // 8192
  _Float16* Wr2t = Wl2t + 8192;                           // 8192
  _Float16* Wlint = Wr2t + 8192;                          // 8192

  float* A = (float*)d_out;
  float* z = A + (size_t)N_NODES * N_NODES;
  float* xo = z + (size_t)N_NODES * 64;

  (void)hipMemsetAsync(deg, 0, N_NODES * sizeof(int), stream);
  hist_prep_kernel<<<3077, 256, 0, stream>>>(edst, deg, x, xh,
                                             W_l1, W_r1, W_l2, W_r2, W_lin,
                                             Wl1t, Wr1t, Wl2t, Wr2t, Wlint);
  scan_kernel<<<1, 1024, 0, stream>>>(deg, row_ptr, cursor, deg_inv);
  scatter_kernel<<<N_EDGES / 256, 256, 0, stream>>>(esrc, edst, cursor, col_idx);

  aggregate_f16_kernel<<<N_NODES / 8, 512, 0, stream>>>(xh, row_ptr, col_idx, deg_inv, aggh);
  sage1_mfma_kernel<<<N_NODES / 64, 256, 0, stream>>>(aggh, xh, Wl1t, Wr1t, b1, hh);
  aggregate_f16_kernel<<<N_NODES / 8, 512, 0, stream>>>(hh, row_ptr, col_idx, deg_inv, aggh);
  sage2_fused_kernel<<<N_NODES / 64, 256, 0, stream>>>(aggh, hh, Wl2t, Wr2t, b2,
                                                       Wlint, b_lin, z, zh, xo);

  apred_kernel<<<8192, 512, 0, stream>>>(zh, A);
}